// Round 2
// baseline (119.794 us; speedup 1.0000x reference)
//
#include <hip/hip_runtime.h>

// DiversityLoss: reference collapses to
//   out = (||colsum||^2 - B * sum(x^2)) / (D * B * (B-1))
// B=64, D=3*256*256=196608. Single memory-bound pass over 50.3 MB fp32.
//
// Round 3 (fix): __builtin_nontemporal_load needs a native vector type, not
// HIP_vector_type<float,4>. Use ext_vector_type(4) float for the streaming
// loads. Fused finalize via last-block ticket (rocPRIM decoupled pattern):
// 4-byte memset node zeroes the ticket; each block writes its deterministic
// partial slot, bumps the ticket with acq_rel; the 768th arrival reduces the
// 768 partials and writes out. Removes one graph dispatch + finalize drain.

#define NBLK 768   // = D4 / 64 column-tiles; also 3 * 256 for the final reduce

typedef float f4 __attribute__((ext_vector_type(4)));

__global__ __launch_bounds__(256) void div_fused(const f4* __restrict__ x4,
                                                 float* __restrict__ partial,
                                                 unsigned int* __restrict__ ticket,
                                                 float* __restrict__ out,
                                                 int D4, float scale) {
    const int lane = threadIdx.x & 63;          // float4-column within tile
    const int rg   = threadIdx.x >> 6;          // row-group 0..3 (16 rows each)
    const int col  = blockIdx.x * 64 + lane;

    const f4* p = x4 + (size_t)rg * 16 * (size_t)D4 + col;

    float sx = 0.f, sy = 0.f, sz = 0.f, sw = 0.f;
    float sq = 0.f;

    #pragma unroll
    for (int r = 0; r < 16; ++r) {
        f4 v = __builtin_nontemporal_load(&p[(size_t)r * (size_t)D4]);
        sx += v.x; sy += v.y; sz += v.z; sw += v.w;
        sq = fmaf(v.x, v.x, sq);
        sq = fmaf(v.y, v.y, sq);
        sq = fmaf(v.z, v.z, sq);
        sq = fmaf(v.w, v.w, sq);
    }

    // Every thread contributes -B * sum(x^2) for its chunk.
    float contrib = -64.0f * sq;

    // Combine partial column sums across the 4 row-groups, square on rg 0.
    __shared__ float part[3][4][64];
    if (rg > 0) {
        part[rg - 1][0][lane] = sx;
        part[rg - 1][1][lane] = sy;
        part[rg - 1][2][lane] = sz;
        part[rg - 1][3][lane] = sw;
    }
    __syncthreads();
    if (rg == 0) {
        #pragma unroll
        for (int g = 0; g < 3; ++g) {
            sx += part[g][0][lane];
            sy += part[g][1][lane];
            sz += part[g][2][lane];
            sw += part[g][3][lane];
        }
        contrib += sx * sx + sy * sy + sz * sz + sw * sw;
    }

    // Block reduction: wave-64 shuffle, then 4 wave results via LDS.
    #pragma unroll
    for (int off = 32; off > 0; off >>= 1)
        contrib += __shfl_down(contrib, off, 64);

    __shared__ float wsum[4];
    __shared__ bool isLast;
    if (lane == 0) wsum[rg] = contrib;
    __syncthreads();

    if (threadIdx.x == 0) {
        float bsum = wsum[0] + wsum[1] + wsum[2] + wsum[3];
        // Deterministic per-block slot; acq_rel ticket bump orders it.
        __hip_atomic_store(&partial[blockIdx.x], bsum,
                           __ATOMIC_RELAXED, __HIP_MEMORY_SCOPE_AGENT);
        unsigned int old = __hip_atomic_fetch_add(ticket, 1u,
                           __ATOMIC_ACQ_REL, __HIP_MEMORY_SCOPE_AGENT);
        isLast = (old == NBLK - 1);
    }
    __syncthreads();
    if (!isLast) return;

    // Last block: all 767 other partials are globally visible (each writer's
    // store ordered before its ticket bump; our acq_rel add synchronized).
    const int t = threadIdx.x;
    float v = __hip_atomic_load(&partial[t],       __ATOMIC_RELAXED, __HIP_MEMORY_SCOPE_AGENT)
            + __hip_atomic_load(&partial[t + 256], __ATOMIC_RELAXED, __HIP_MEMORY_SCOPE_AGENT)
            + __hip_atomic_load(&partial[t + 512], __ATOMIC_RELAXED, __HIP_MEMORY_SCOPE_AGENT);

    #pragma unroll
    for (int off = 32; off > 0; off >>= 1)
        v += __shfl_down(v, off, 64);

    __syncthreads();                // wsum reuse: everyone is past earlier reads
    if (lane == 0) wsum[rg] = v;
    __syncthreads();
    if (t == 0)
        out[0] = (wsum[0] + wsum[1] + wsum[2] + wsum[3]) * scale;
}

extern "C" void kernel_launch(void* const* d_in, const int* in_sizes, int n_in,
                              void* d_out, int out_size, void* d_ws, size_t ws_size,
                              hipStream_t stream) {
    const float* x = (const float*)d_in[0];
    float* out = (float*)d_out;
    float* partial = (float*)d_ws;
    unsigned int* ticket = (unsigned int*)((char*)d_ws + 4096);

    const int B = 64;
    const int total = in_sizes[0];          // 12,582,912 elements
    const int D = total / B;                // 196,608
    const int D4 = D / 4;                   // 49,152

    const float scale = (float)(1.0 / ((double)D * (double)B * (double)(B - 1)));

    // Graph-capturable memset node: zero the arrival ticket each replay.
    (void)hipMemsetAsync(ticket, 0, sizeof(unsigned int), stream);
    div_fused<<<NBLK, 256, 0, stream>>>((const f4*)x, partial, ticket, out,
                                        D4, scale);
}

// Round 3
// 102.744 us; speedup vs baseline: 1.1659x; 1.1659x over previous
//
#include <hip/hip_runtime.h>

// DiversityLoss: reference collapses to
//   out = (||colsum||^2 - B * sum(x^2)) / (D * B * (B-1))
// B=64, D=3*256*256=196608. Single memory-bound pass over 50.3 MB fp32.
//
// Round 3 -> 4: REVERTED the nontemporal-load hint. nt defeats L3 residency
// of the re-read input (50.3 MB fits the 256 MiB Infinity Cache across graph
// replays); round-3 counters showed 552 GB/s / 1.5% VALU / 45.7 us — a
// latency-bound cache-bypass regression, not a win. Plain loads restore the
// cache-served fast path. Fused finalize via last-block ticket kept (verified
// correct, absmax 0): 4-byte memset zeroes the ticket; each block writes its
// deterministic partial slot, bumps the ticket acq_rel; 768th arrival reduces.

#define NBLK 768   // = D4 / 64 column-tiles; also 3 * 256 for the final reduce

__global__ __launch_bounds__(256) void div_fused(const float4* __restrict__ x4,
                                                 float* __restrict__ partial,
                                                 unsigned int* __restrict__ ticket,
                                                 float* __restrict__ out,
                                                 int D4, float scale) {
    const int lane = threadIdx.x & 63;          // float4-column within tile
    const int rg   = threadIdx.x >> 6;          // row-group 0..3 (16 rows each)
    const int col  = blockIdx.x * 64 + lane;

    const float4* p = x4 + (size_t)rg * 16 * (size_t)D4 + col;

    float sx = 0.f, sy = 0.f, sz = 0.f, sw = 0.f;
    float sq = 0.f;

    #pragma unroll
    for (int r = 0; r < 16; ++r) {
        float4 v = p[(size_t)r * (size_t)D4];
        sx += v.x; sy += v.y; sz += v.z; sw += v.w;
        sq = fmaf(v.x, v.x, sq);
        sq = fmaf(v.y, v.y, sq);
        sq = fmaf(v.z, v.z, sq);
        sq = fmaf(v.w, v.w, sq);
    }

    // Every thread contributes -B * sum(x^2) for its chunk.
    float contrib = -64.0f * sq;

    // Combine partial column sums across the 4 row-groups, square on rg 0.
    __shared__ float4 part[3][64];
    if (rg > 0) part[rg - 1][lane] = make_float4(sx, sy, sz, sw);
    __syncthreads();
    if (rg == 0) {
        #pragma unroll
        for (int g = 0; g < 3; ++g) {
            float4 t = part[g][lane];
            sx += t.x; sy += t.y; sz += t.z; sw += t.w;
        }
        contrib += sx * sx + sy * sy + sz * sz + sw * sw;
    }

    // Block reduction: wave-64 shuffle, then 4 wave results via LDS.
    #pragma unroll
    for (int off = 32; off > 0; off >>= 1)
        contrib += __shfl_down(contrib, off, 64);

    __shared__ float wsum[4];
    __shared__ bool isLast;
    if (lane == 0) wsum[rg] = contrib;
    __syncthreads();

    if (threadIdx.x == 0) {
        float bsum = wsum[0] + wsum[1] + wsum[2] + wsum[3];
        // Deterministic per-block slot; acq_rel ticket bump orders it.
        __hip_atomic_store(&partial[blockIdx.x], bsum,
                           __ATOMIC_RELAXED, __HIP_MEMORY_SCOPE_AGENT);
        unsigned int old = __hip_atomic_fetch_add(ticket, 1u,
                           __ATOMIC_ACQ_REL, __HIP_MEMORY_SCOPE_AGENT);
        isLast = (old == NBLK - 1);
    }
    __syncthreads();
    if (!isLast) return;

    // Last block: all 767 other partials are globally visible (each writer's
    // store ordered before its ticket bump; our acq_rel add synchronized).
    const int t = threadIdx.x;
    float v = __hip_atomic_load(&partial[t],       __ATOMIC_RELAXED, __HIP_MEMORY_SCOPE_AGENT)
            + __hip_atomic_load(&partial[t + 256], __ATOMIC_RELAXED, __HIP_MEMORY_SCOPE_AGENT)
            + __hip_atomic_load(&partial[t + 512], __ATOMIC_RELAXED, __HIP_MEMORY_SCOPE_AGENT);

    #pragma unroll
    for (int off = 32; off > 0; off >>= 1)
        v += __shfl_down(v, off, 64);

    __syncthreads();                // wsum reuse: everyone is past earlier reads
    if (lane == 0) wsum[rg] = v;
    __syncthreads();
    if (t == 0)
        out[0] = (wsum[0] + wsum[1] + wsum[2] + wsum[3]) * scale;
}

extern "C" void kernel_launch(void* const* d_in, const int* in_sizes, int n_in,
                              void* d_out, int out_size, void* d_ws, size_t ws_size,
                              hipStream_t stream) {
    const float* x = (const float*)d_in[0];
    float* out = (float*)d_out;
    float* partial = (float*)d_ws;
    unsigned int* ticket = (unsigned int*)((char*)d_ws + 4096);

    const int B = 64;
    const int total = in_sizes[0];          // 12,582,912 elements
    const int D = total / B;                // 196,608
    const int D4 = D / 4;                   // 49,152

    const float scale = (float)(1.0 / ((double)D * (double)B * (double)(B - 1)));

    // Graph-capturable memset node: zero the arrival ticket each replay.
    (void)hipMemsetAsync(ticket, 0, sizeof(unsigned int), stream);
    div_fused<<<NBLK, 256, 0, stream>>>((const float4*)x, partial, ticket, out,
                                        D4, scale);
}

// Round 4
// 80.485 us; speedup vs baseline: 1.4884x; 1.2766x over previous
//
#include <hip/hip_runtime.h>

// DiversityLoss: reference collapses to
//   out = (||colsum||^2 - B * sum(x^2)) / (D * B * (B-1))
// B=64, D=3*256*256=196608. Single memory-bound pass over 50.3 MB fp32.
//
// Round 4: reverted the fused last-block ticket (768 agent-scope acq_rel RMWs
// cost ~14 us in L2 maintenance — fused kernel measured 45 us vs ~31 us for
// the plain split main). Back to deterministic per-block slots + tiny
// finalize dispatch. Attack the real limiter instead: the streaming pass ran
// at 1.1-1.6 TB/s (latency-bound, 12 waves/CU, Occupancy 23%, VALUBusy 1.5%).
// Now 1024 threads/block (16 row-groups x 4 rows), still full 64-row column
// tile per block -> 12288 waves, 2 blocks/CU resident = 32 waves/CU max
// occupancy. Same coalescing (64-lane x float4 = 1 KB per wave-load).

#define NBLK 768   // = D4 / 64 column-tiles; also 3 * 256 for the final reduce

__global__ __launch_bounds__(1024) void div_main(const float4* __restrict__ x4,
                                                 float* __restrict__ partial,
                                                 int D4) {
    const int lane = threadIdx.x & 63;          // float4-column within tile
    const int rg   = threadIdx.x >> 6;          // row-group 0..15 (4 rows each)
    const int col  = blockIdx.x * 64 + lane;

    const float4* p = x4 + (size_t)rg * 4 * (size_t)D4 + col;

    float sx = 0.f, sy = 0.f, sz = 0.f, sw = 0.f;
    float sq = 0.f;

    #pragma unroll
    for (int r = 0; r < 4; ++r) {
        float4 v = p[(size_t)r * (size_t)D4];
        sx += v.x; sy += v.y; sz += v.z; sw += v.w;
        sq = fmaf(v.x, v.x, sq);
        sq = fmaf(v.y, v.y, sq);
        sq = fmaf(v.z, v.z, sq);
        sq = fmaf(v.w, v.w, sq);
    }

    // Every thread contributes -B * sum(x^2) for its chunk.
    float contrib = -64.0f * sq;

    // Combine partial column sums across the 16 row-groups, square on rg 0.
    __shared__ float4 part[16][64];
    part[rg][lane] = make_float4(sx, sy, sz, sw);
    __syncthreads();
    if (rg == 0) {
        #pragma unroll
        for (int g = 1; g < 16; ++g) {
            float4 t = part[g][lane];
            sx += t.x; sy += t.y; sz += t.z; sw += t.w;
        }
        contrib += sx * sx + sy * sy + sz * sz + sw * sw;
    }

    // Block reduction: wave-64 shuffle, then 16 wave results via LDS.
    #pragma unroll
    for (int off = 32; off > 0; off >>= 1)
        contrib += __shfl_down(contrib, off, 64);

    __shared__ float wsum[16];
    if (lane == 0) wsum[rg] = contrib;
    __syncthreads();
    if (threadIdx.x == 0) {
        float s = 0.f;
        #pragma unroll
        for (int g = 0; g < 16; ++g) s += wsum[g];
        partial[blockIdx.x] = s;
    }
}

__global__ __launch_bounds__(256) void div_finalize(const float* __restrict__ partial,
                                                    float* __restrict__ out,
                                                    float scale) {
    const int t = threadIdx.x;
    float v = partial[t] + partial[t + 256] + partial[t + 512];

    #pragma unroll
    for (int off = 32; off > 0; off >>= 1)
        v += __shfl_down(v, off, 64);

    __shared__ float wsum[4];
    if ((t & 63) == 0) wsum[t >> 6] = v;
    __syncthreads();
    if (t == 0)
        out[0] = (wsum[0] + wsum[1] + wsum[2] + wsum[3]) * scale;
}

extern "C" void kernel_launch(void* const* d_in, const int* in_sizes, int n_in,
                              void* d_out, int out_size, void* d_ws, size_t ws_size,
                              hipStream_t stream) {
    const float* x = (const float*)d_in[0];
    float* out = (float*)d_out;
    float* partial = (float*)d_ws;

    const int B = 64;
    const int total = in_sizes[0];          // 12,582,912 elements
    const int D = total / B;                // 196,608
    const int D4 = D / 4;                   // 49,152

    const float scale = (float)(1.0 / ((double)D * (double)B * (double)(B - 1)));

    div_main<<<NBLK, 1024, 0, stream>>>((const float4*)x, partial, D4);
    div_finalize<<<1, 256, 0, stream>>>(partial, out, scale);
}

// Round 5
// 79.226 us; speedup vs baseline: 1.5120x; 1.0159x over previous
//
#include <hip/hip_runtime.h>

// DiversityLoss: reference collapses to
//   out = (||colsum||^2 - B * sum(x^2)) / (D * B * (B-1))
// B=64, D=3*256*256=196608. Single memory-bound pass over 50.3 MB fp32.
//
// Round 5: attack DRAM burst granularity. Previous layout (64-f4-wide column
// tiles) made every page-visit a 1 KB burst at 786 KB row stride — ~12K
// interleaved 1 KB streams ran at 1.1-1.6 TB/s (page thrash). Occupancy max
// (round 4) changed nothing, killing the latency theory. Now: 192 blocks x
// 1024 threads, block owns a 256-f4-wide x 64-row tile; 8 rowgroups x 8 rows;
// each thread covers cols (c, c+128) so each row-visit is a 4 KB contiguous
// slab and consecutive per-thread loads stay in the same 4 KB window.
// Still single-pass: full column in block -> one scalar partial per block.

#define NBLK 192   // = 49152 / 256 column tiles

__global__ __launch_bounds__(1024) void div_main(const float4* __restrict__ x4,
                                                 float* __restrict__ partial,
                                                 int D4) {
    const int c  = threadIdx.x & 127;           // column-thread 0..127
    const int rg = threadIdx.x >> 7;            // rowgroup 0..7 (8 rows each)
    const size_t col0 = (size_t)blockIdx.x * 256 + c;

    const float4* p = x4 + (size_t)(rg * 8) * (size_t)D4 + col0;

    float4 a0 = make_float4(0.f, 0.f, 0.f, 0.f);
    float4 a1 = make_float4(0.f, 0.f, 0.f, 0.f);
    float sq = 0.f;

    #pragma unroll
    for (int r = 0; r < 8; ++r) {
        float4 v0 = p[(size_t)r * (size_t)D4];        // col c      of row
        float4 v1 = p[(size_t)r * (size_t)D4 + 128];  // col c+128  of row
        a0.x += v0.x; a0.y += v0.y; a0.z += v0.z; a0.w += v0.w;
        a1.x += v1.x; a1.y += v1.y; a1.z += v1.z; a1.w += v1.w;
        sq = fmaf(v0.x, v0.x, sq); sq = fmaf(v0.y, v0.y, sq);
        sq = fmaf(v0.z, v0.z, sq); sq = fmaf(v0.w, v0.w, sq);
        sq = fmaf(v1.x, v1.x, sq); sq = fmaf(v1.y, v1.y, sq);
        sq = fmaf(v1.z, v1.z, sq); sq = fmaf(v1.w, v1.w, sq);
    }

    // Every thread contributes -B * sum(x^2) for its 64 elements.
    float contrib = -64.0f * sq;

    // Combine partial column sums across the 8 row-groups, square on rg 0.
    __shared__ float4 part[8][256];
    part[rg][c]       = a0;
    part[rg][c + 128] = a1;
    __syncthreads();
    if (rg == 0) {
        #pragma unroll
        for (int g = 1; g < 8; ++g) {
            float4 t0 = part[g][c];
            float4 t1 = part[g][c + 128];
            a0.x += t0.x; a0.y += t0.y; a0.z += t0.z; a0.w += t0.w;
            a1.x += t1.x; a1.y += t1.y; a1.z += t1.z; a1.w += t1.w;
        }
        contrib += a0.x * a0.x + a0.y * a0.y + a0.z * a0.z + a0.w * a0.w
                 + a1.x * a1.x + a1.y * a1.y + a1.z * a1.z + a1.w * a1.w;
    }

    // Block reduction: wave-64 shuffle, then 16 wave results via LDS.
    #pragma unroll
    for (int off = 32; off > 0; off >>= 1)
        contrib += __shfl_down(contrib, off, 64);

    __shared__ float wsum[16];
    const int wave = threadIdx.x >> 6;
    if ((threadIdx.x & 63) == 0) wsum[wave] = contrib;
    __syncthreads();
    if (threadIdx.x == 0) {
        float s = 0.f;
        #pragma unroll
        for (int g = 0; g < 16; ++g) s += wsum[g];
        partial[blockIdx.x] = s;
    }
}

__global__ __launch_bounds__(256) void div_finalize(const float* __restrict__ partial,
                                                    float* __restrict__ out,
                                                    float scale) {
    const int t = threadIdx.x;
    float v = (t < NBLK) ? partial[t] : 0.f;

    #pragma unroll
    for (int off = 32; off > 0; off >>= 1)
        v += __shfl_down(v, off, 64);

    __shared__ float wsum[4];
    if ((t & 63) == 0) wsum[t >> 6] = v;
    __syncthreads();
    if (t == 0)
        out[0] = (wsum[0] + wsum[1] + wsum[2] + wsum[3]) * scale;
}

extern "C" void kernel_launch(void* const* d_in, const int* in_sizes, int n_in,
                              void* d_out, int out_size, void* d_ws, size_t ws_size,
                              hipStream_t stream) {
    const float* x = (const float*)d_in[0];
    float* out = (float*)d_out;
    float* partial = (float*)d_ws;

    const int B = 64;
    const int total = in_sizes[0];          // 12,582,912 elements
    const int D = total / B;                // 196,608
    const int D4 = D / 4;                   // 49,152

    const float scale = (float)(1.0 / ((double)D * (double)B * (double)(B - 1)));

    div_main<<<NBLK, 1024, 0, stream>>>((const float4*)x, partial, D4);
    div_finalize<<<1, 256, 0, stream>>>(partial, out, scale);
}